// Round 3
// baseline (546.138 us; speedup 1.0000x reference)
//
#include <hip/hip_runtime.h>

#define NDIM 512
#define CZ 128
#define NN (NDIM*NDIM)

typedef __attribute__((ext_vector_type(8))) short short8;
typedef __attribute__((ext_vector_type(4))) float f32x4;
typedef unsigned short ushort_t;

__device__ __forceinline__ ushort_t f2b(float f) {
  unsigned int x = __float_as_uint(f);
  unsigned int r = (x + 0x7fffu + ((x >> 16) & 1u)) >> 16;
  return (ushort_t)r;
}
__device__ __forceinline__ float b2f(ushort_t u) {
  return __uint_as_float(((unsigned int)u) << 16);
}
__device__ __forceinline__ float fast_sigmoid(float x) {
  return __builtin_amdgcn_rcpf(1.0f + __expf(-x));
}

// ---------------- K0: convert weights to bf16, concatenated ----------------
// Wcat order: 0:Wga 1:Wa 2:Wgb 3:Wb 4:Wog 5:Wo
__global__ __launch_bounds__(256) void k_wconv(
    const float* __restrict__ Wga, const float* __restrict__ Wa,
    const float* __restrict__ Wgb, const float* __restrict__ Wb,
    const float* __restrict__ Wog, const float* __restrict__ Wo,
    ushort_t* __restrict__ Wcat) {
  int idx = blockIdx.x * 256 + threadIdx.x;  // 6*16384 total
  const float* srcs[6] = {Wga, Wa, Wgb, Wb, Wog, Wo};
  float v = srcs[idx >> 14][idx & 16383];
  Wcat[idx] = f2b(v);
}

// ---------------- K_front: fused LN + 5 projections ------------------------
// Per block: 64 m-rows. LN(z) -> zt (LDS, bf16). Then 3 passes:
//   pass0: a  = sigmoid(Wga zn + bga) * (Wa zn + ba) -> a_cm [c][m]
//   pass1: b  = sigmoid(Wgb zn + bgb) * (Wb zn + bb) -> b_cm [c][m]
//   pass2: og = sigmoid(Wog zn + bog)                -> og_rm [m][c]
// Wave w owns c-slice [32w, 32w+32), all 64 m. acc layout (verified R1):
//   c = wc + cs*16 + lq*4 + r, m = m0 + ms*16 + lr.
__global__ __launch_bounds__(256, 4) void k_front(
    const float* __restrict__ z, const float* __restrict__ gamma,
    const float* __restrict__ beta, const ushort_t* __restrict__ Wcat,
    const float* __restrict__ bga, const float* __restrict__ ba,
    const float* __restrict__ bgb, const float* __restrict__ bb,
    const float* __restrict__ bog,
    ushort_t* __restrict__ a_cm, ushort_t* __restrict__ b_cm,
    ushort_t* __restrict__ og_rm) {
  __shared__ ushort_t zt[64 * 136];  // [64 m][128 k] bf16, stride 136
  const int t = threadIdx.x;
  const int m0 = blockIdx.x * 64;
  const int lane = t & 63, wid = t >> 6;

  // --- LN phase: each wave 16 rows, 2 rows per iteration (32 lanes/row) ---
  {
    const int sub = lane >> 5;   // which of the 2 rows
    const int sc = lane & 31;    // col group (4 floats)
    float4 g4 = *reinterpret_cast<const float4*>(gamma + sc * 4);
    float4 e4 = *reinterpret_cast<const float4*>(beta + sc * 4);
#pragma unroll
    for (int it = 0; it < 8; it++) {
      int row = wid * 16 + it * 2 + sub;
      float4 v = *reinterpret_cast<const float4*>(z + (size_t)(m0 + row) * CZ + sc * 4);
      float s = v.x + v.y + v.z + v.w;
      float ss = v.x * v.x + v.y * v.y + v.z * v.z + v.w * v.w;
#pragma unroll
      for (int o = 1; o < 32; o <<= 1) { s += __shfl_xor(s, o); ss += __shfl_xor(ss, o); }
      float mu = s * (1.0f / CZ);
      float inv = rsqrtf(fmaxf(ss * (1.0f / CZ) - mu * mu, 0.0f) + 1e-5f);
      unsigned int p0 = (unsigned int)f2b((v.x - mu) * inv * g4.x + e4.x) |
                        ((unsigned int)f2b((v.y - mu) * inv * g4.y + e4.y) << 16);
      unsigned int p1 = (unsigned int)f2b((v.z - mu) * inv * g4.z + e4.z) |
                        ((unsigned int)f2b((v.w - mu) * inv * g4.w + e4.w) << 16);
      uint2 pk; pk.x = p0; pk.y = p1;
      *reinterpret_cast<uint2*>(&zt[row * 136 + sc * 4]) = pk;
    }
  }
  __syncthreads();

  const int lr = lane & 15, lq = lane >> 4;
  const int wc = wid * 32;

  // --- gated pass-pairs: a (pass 0), b (pass 1) ---
#pragma unroll 1
  for (int pass = 0; pass < 2; pass++) {
    const ushort_t* Wg = Wcat + (size_t)(pass * 2) * 16384;
    const ushort_t* Wv = Wg + 16384;
    const float* bg = pass ? bgb : bga;
    const float* bv = pass ? bb : ba;
    ushort_t* outp = pass ? b_cm : a_cm;
    f32x4 aG[2][4], aV[2][4];
#pragma unroll
    for (int cs = 0; cs < 2; cs++)
#pragma unroll
      for (int ms = 0; ms < 4; ms++) {
        aG[cs][ms] = (f32x4){0.f, 0.f, 0.f, 0.f};
        aV[cs][ms] = (f32x4){0.f, 0.f, 0.f, 0.f};
      }
#pragma unroll
    for (int kk = 0; kk < 128; kk += 32) {
      short8 zf[4];
#pragma unroll
      for (int ms = 0; ms < 4; ms++)
        zf[ms] = *reinterpret_cast<const short8*>(&zt[(ms * 16 + lr) * 136 + kk + lq * 8]);
#pragma unroll
      for (int cs = 0; cs < 2; cs++) {
        short8 wg = *reinterpret_cast<const short8*>(
            Wg + (size_t)(wc + cs * 16 + lr) * CZ + kk + lq * 8);
        short8 wv = *reinterpret_cast<const short8*>(
            Wv + (size_t)(wc + cs * 16 + lr) * CZ + kk + lq * 8);
#pragma unroll
        for (int ms = 0; ms < 4; ms++) {
          aG[cs][ms] = __builtin_amdgcn_mfma_f32_16x16x32_bf16(wg, zf[ms], aG[cs][ms], 0, 0, 0);
          aV[cs][ms] = __builtin_amdgcn_mfma_f32_16x16x32_bf16(wv, zf[ms], aV[cs][ms], 0, 0, 0);
        }
      }
    }
#pragma unroll
    for (int cs = 0; cs < 2; cs++)
#pragma unroll
      for (int r = 0; r < 4; r++) {
        int c = wc + cs * 16 + lq * 4 + r;
        float bgc = bg[c], bvc = bv[c];
#pragma unroll
        for (int ms = 0; ms < 4; ms++) {
          float val = (aV[cs][ms][r] + bvc) * fast_sigmoid(aG[cs][ms][r] + bgc);
          outp[(size_t)c * NN + m0 + ms * 16 + lr] = f2b(val);
        }
      }
  }

  // --- og pass ---
  {
    const ushort_t* Wg = Wcat + (size_t)4 * 16384;
    f32x4 aG[2][4];
#pragma unroll
    for (int cs = 0; cs < 2; cs++)
#pragma unroll
      for (int ms = 0; ms < 4; ms++) aG[cs][ms] = (f32x4){0.f, 0.f, 0.f, 0.f};
#pragma unroll
    for (int kk = 0; kk < 128; kk += 32) {
      short8 zf[4];
#pragma unroll
      for (int ms = 0; ms < 4; ms++)
        zf[ms] = *reinterpret_cast<const short8*>(&zt[(ms * 16 + lr) * 136 + kk + lq * 8]);
#pragma unroll
      for (int cs = 0; cs < 2; cs++) {
        short8 wg = *reinterpret_cast<const short8*>(
            Wg + (size_t)(wc + cs * 16 + lr) * CZ + kk + lq * 8);
#pragma unroll
        for (int ms = 0; ms < 4; ms++)
          aG[cs][ms] = __builtin_amdgcn_mfma_f32_16x16x32_bf16(wg, zf[ms], aG[cs][ms], 0, 0, 0);
      }
    }
#pragma unroll
    for (int cs = 0; cs < 2; cs++)
#pragma unroll
      for (int r = 0; r < 4; r++) {
        int c = wc + cs * 16 + lq * 4 + r;
        float bc = bog[c];
#pragma unroll
        for (int ms = 0; ms < 4; ms++) {
          og_rm[(size_t)(m0 + ms * 16 + lr) * CZ + c] = f2b(fast_sigmoid(aG[cs][ms][r] + bc));
        }
      }
  }
}

// ---------------- K3: per-channel einsum U_c = A_c * B_c^T ----------------
// a_cm/b_cm/u_cm are [c][i*N+k] channel-major bf16. 1-D grid, XCD swizzle.
__global__ __launch_bounds__(256) void k_tri(
    const ushort_t* __restrict__ a_cm, const ushort_t* __restrict__ b_cm,
    ushort_t* __restrict__ u_cm) {
  __shared__ ushort_t sh[18432];  // lA[128*72] + lB[128*72]; reused as out[128*136]
  ushort_t* lA = sh;
  ushort_t* lB = sh + 9216;
  const int t = threadIdx.x;
  // bijective XCD swizzle: 2048 blocks, 8 XCDs, 256 per chunk
  int swz = (blockIdx.x & 7) * 256 + (blockIdx.x >> 3);
  const int ch = swz >> 4;
  const int i0 = ((swz >> 2) & 3) * 128, j0 = (swz & 3) * 128;
  const size_t base = (size_t)ch * NN;
  const int wid = t >> 6, lane = t & 63, lr = lane & 15, lq = lane >> 4;
  const int wi = (wid >> 1) * 64, wj = (wid & 1) * 64;
  f32x4 acc[4][4];
#pragma unroll
  for (int si = 0; si < 4; si++)
#pragma unroll
    for (int sj = 0; sj < 4; sj++) acc[si][sj] = (f32x4){0.f, 0.f, 0.f, 0.f};

  for (int kb = 0; kb < 8; kb++) {
    const int k0 = kb * 64;
#pragma unroll
    for (int p = 0; p < 4; p++) {
      int lin = p * 256 + t;
      int row = lin >> 3, cq = lin & 7;
      *reinterpret_cast<short8*>(&lA[row * 72 + cq * 8]) =
          *reinterpret_cast<const short8*>(a_cm + base + (size_t)(i0 + row) * NDIM + k0 + cq * 8);
      *reinterpret_cast<short8*>(&lB[row * 72 + cq * 8]) =
          *reinterpret_cast<const short8*>(b_cm + base + (size_t)(j0 + row) * NDIM + k0 + cq * 8);
    }
    __syncthreads();
#pragma unroll
    for (int ks = 0; ks < 2; ks++) {
      short8 af[4], bf[4];
#pragma unroll
      for (int s = 0; s < 4; s++) {
        af[s] = *reinterpret_cast<const short8*>(&lA[(wi + s * 16 + lr) * 72 + ks * 32 + lq * 8]);
        bf[s] = *reinterpret_cast<const short8*>(&lB[(wj + s * 16 + lr) * 72 + ks * 32 + lq * 8]);
      }
#pragma unroll
      for (int si = 0; si < 4; si++)
#pragma unroll
        for (int sj = 0; sj < 4; sj++)
          acc[si][sj] = __builtin_amdgcn_mfma_f32_16x16x32_bf16(
              af[si], bf[sj], acc[si][sj], 0, 0, 0);
    }
    __syncthreads();
  }
  // epilogue -> LDS staging [128 i][128 j], stride 136
#pragma unroll
  for (int si = 0; si < 4; si++)
#pragma unroll
    for (int sj = 0; sj < 4; sj++)
#pragma unroll
      for (int r = 0; r < 4; r++) {
        int il = wi + si * 16 + lq * 4 + r;
        int jl = wj + sj * 16 + lr;
        sh[il * 136 + jl] = f2b(acc[si][sj][r]);
      }
  __syncthreads();
#pragma unroll
  for (int p = 0; p < 8; p++) {
    int lin = p * 256 + t;
    int row = lin >> 4, col = (lin & 15) * 8;
    *reinterpret_cast<short8*>(u_cm + base + (size_t)(i0 + row) * NDIM + j0 + col) =
        *reinterpret_cast<const short8*>(&sh[row * 136 + col]);
  }
}

// ---------------- K4: out = z + og * (U^T Wo^T + bo) ----------------------
__global__ __launch_bounds__(256) void k_out(
    const ushort_t* __restrict__ u_cm, const ushort_t* __restrict__ WoB,
    const ushort_t* __restrict__ og_rm, const float* __restrict__ z,
    const float* __restrict__ bo, float* __restrict__ out) {
  __shared__ ushort_t lu[128 * 136];  // [c][m-tile], stride 136
  const int t = threadIdx.x;
  const int m0 = blockIdx.x * 128;
#pragma unroll
  for (int p = 0; p < 8; p++) {
    int lin = p * 256 + t;
    int cr = lin >> 4, ch = lin & 15;
    *reinterpret_cast<short8*>(&lu[cr * 136 + ch * 8]) =
        *reinterpret_cast<const short8*>(u_cm + (size_t)cr * NN + m0 + ch * 8);
  }
  __syncthreads();
  const int wid = t >> 6, lane = t & 63, lr = lane & 15, lq = lane >> 4;
  const int wm = (wid >> 1) * 64, wc = (wid & 1) * 64;
  f32x4 acc[4][4];
#pragma unroll
  for (int ms = 0; ms < 4; ms++)
#pragma unroll
    for (int cs = 0; cs < 4; cs++) acc[ms][cs] = (f32x4){0.f, 0.f, 0.f, 0.f};
#pragma unroll
  for (int kk = 0; kk < 128; kk += 32) {
    short8 af[4];
#pragma unroll
    for (int ms = 0; ms < 4; ms++) {
      short8 v;
#pragma unroll
      for (int jj = 0; jj < 8; jj++)
        v[jj] = (short)lu[(kk + lq * 8 + jj) * 136 + wm + ms * 16 + lr];
      af[ms] = v;
    }
#pragma unroll
    for (int cs = 0; cs < 4; cs++) {
      short8 bf = *reinterpret_cast<const short8*>(
          WoB + (size_t)(wc + cs * 16 + lr) * CZ + kk + lq * 8);
#pragma unroll
      for (int ms = 0; ms < 4; ms++)
        acc[ms][cs] = __builtin_amdgcn_mfma_f32_16x16x32_bf16(
            af[ms], bf, acc[ms][cs], 0, 0, 0);
    }
  }
#pragma unroll
  for (int ms = 0; ms < 4; ms++)
#pragma unroll
    for (int cs = 0; cs < 4; cs++)
#pragma unroll
      for (int r = 0; r < 4; r++) {
        int m = m0 + wm + ms * 16 + lq * 4 + r;
        int cp = wc + cs * 16 + lr;
        float val = acc[ms][cs][r] + bo[cp];
        float gate = b2f(og_rm[(size_t)m * CZ + cp]);
        out[(size_t)m * CZ + cp] = z[(size_t)m * CZ + cp] + gate * val;
      }
}

extern "C" void kernel_launch(void* const* d_in, const int* in_sizes, int n_in,
                              void* d_out, int out_size, void* d_ws, size_t ws_size,
                              hipStream_t stream) {
  const float* z = (const float*)d_in[0];
  const float* gamma = (const float*)d_in[1];
  const float* beta = (const float*)d_in[2];
  const float* Wa = (const float*)d_in[3];  const float* ba = (const float*)d_in[4];
  const float* Wb = (const float*)d_in[5];  const float* bb = (const float*)d_in[6];
  const float* Wga = (const float*)d_in[7]; const float* bga = (const float*)d_in[8];
  const float* Wgb = (const float*)d_in[9]; const float* bgb = (const float*)d_in[10];
  const float* Wo = (const float*)d_in[11]; const float* bo = (const float*)d_in[12];
  const float* Wog = (const float*)d_in[13];const float* bog = (const float*)d_in[14];

  char* ws = (char*)d_ws;
  ushort_t* a_cm = (ushort_t*)(ws);                     // 64 MiB [c][m]
  ushort_t* b_cm = (ushort_t*)(ws + 67108864);          // 64 MiB [c][m]
  ushort_t* og_rm = (ushort_t*)(ws + 134217728);        // 64 MiB [m][c]
  ushort_t* u_cm = (ushort_t*)(ws + 201326592);         // 64 MiB [c][i*N+j]
  ushort_t* Wcat = (ushort_t*)(ws + 268435456);         // 192 KiB

  k_wconv<<<384, 256, 0, stream>>>(Wga, Wa, Wgb, Wb, Wog, Wo, Wcat);
  k_front<<<NN / 64, 256, 0, stream>>>(z, gamma, beta, Wcat, bga, ba, bgb, bb, bog,
                                       a_cm, b_cm, og_rm);
  k_tri<<<2048, 256, 0, stream>>>(a_cm, b_cm, u_cm);
  k_out<<<NN / 128, 256, 0, stream>>>(u_cm, Wcat + 5 * 16384, og_rm, z, bo, (float*)d_out);
}

// Round 4
// 384.360 us; speedup vs baseline: 1.4209x; 1.4209x over previous
//
#include <hip/hip_runtime.h>

#define NDIM 512
#define CZ 128
#define NN (NDIM*NDIM)

typedef __attribute__((ext_vector_type(8))) _Float16 half8;
typedef __attribute__((ext_vector_type(8))) short short8;
typedef __attribute__((ext_vector_type(4))) float f32x4;
typedef unsigned short ushort_t;

__device__ __forceinline__ ushort_t f2h(float f) {
  _Float16 h = (_Float16)f;
  return __builtin_bit_cast(unsigned short, h);
}
__device__ __forceinline__ float h2f(ushort_t u) {
  return (float)__builtin_bit_cast(_Float16, u);
}
__device__ __forceinline__ float fast_sigmoid(float x) {
  return __builtin_amdgcn_rcpf(1.0f + __expf(-x));
}
__device__ __forceinline__ half8 ld_h8(const ushort_t* p) {
  return *reinterpret_cast<const half8*>(p);
}

// ---------------- K0: convert weights to fp16, concatenated ----------------
// Wcat order: 0:Wga 1:Wa 2:Wgb 3:Wb 4:Wog 5:Wo
__global__ __launch_bounds__(256) void k_wconv(
    const float* __restrict__ Wga, const float* __restrict__ Wa,
    const float* __restrict__ Wgb, const float* __restrict__ Wb,
    const float* __restrict__ Wog, const float* __restrict__ Wo,
    ushort_t* __restrict__ Wcat) {
  int idx = blockIdx.x * 256 + threadIdx.x;  // 6*16384 total
  const float* srcs[6] = {Wga, Wa, Wgb, Wb, Wog, Wo};
  float v = srcs[idx >> 14][idx & 16383];
  Wcat[idx] = f2h(v);
}

// ---------------- K_front: fused LN + 5 projections ------------------------
// Per block: 64 m-rows. LN(z) -> zt (LDS, fp16). Then:
//   pass0: a  = sigmoid(Wga zn + bga) * (Wa zn + ba) -> a_cm [c][m]
//   pass1: b  = sigmoid(Wgb zn + bgb) * (Wb zn + bb) -> b_cm [c][m]
//   pass2: og = sigmoid(Wog zn + bog)                -> og_rm [m][c]
// All global stores via LDS staging, short8 (>=128B contiguous / instr).
__global__ __launch_bounds__(256, 4) void k_front(
    const float* __restrict__ z, const float* __restrict__ gamma,
    const float* __restrict__ beta, const ushort_t* __restrict__ Wcat,
    const float* __restrict__ bga, const float* __restrict__ ba,
    const float* __restrict__ bgb, const float* __restrict__ bb,
    const float* __restrict__ bog,
    ushort_t* __restrict__ a_cm, ushort_t* __restrict__ b_cm,
    ushort_t* __restrict__ og_rm) {
  __shared__ ushort_t zt[64 * 136];  // [64 m][128 k] fp16, stride 136
  __shared__ ushort_t ot[128 * 72];  // staging [128 c][64 m], stride 72
  const int t = threadIdx.x;
  const int m0 = blockIdx.x * 64;
  const int lane = t & 63, wid = t >> 6;

  // --- LN phase: each wave 16 rows, 2 rows per iteration (32 lanes/row) ---
  {
    const int sub = lane >> 5;
    const int sc = lane & 31;
    float4 g4 = *reinterpret_cast<const float4*>(gamma + sc * 4);
    float4 e4 = *reinterpret_cast<const float4*>(beta + sc * 4);
#pragma unroll
    for (int it = 0; it < 8; it++) {
      int row = wid * 16 + it * 2 + sub;
      float4 v = *reinterpret_cast<const float4*>(z + (size_t)(m0 + row) * CZ + sc * 4);
      float s = v.x + v.y + v.z + v.w;
      float ss = v.x * v.x + v.y * v.y + v.z * v.z + v.w * v.w;
#pragma unroll
      for (int o = 1; o < 32; o <<= 1) { s += __shfl_xor(s, o); ss += __shfl_xor(ss, o); }
      float mu = s * (1.0f / CZ);
      float inv = rsqrtf(fmaxf(ss * (1.0f / CZ) - mu * mu, 0.0f) + 1e-5f);
      unsigned int p0 = (unsigned int)f2h((v.x - mu) * inv * g4.x + e4.x) |
                        ((unsigned int)f2h((v.y - mu) * inv * g4.y + e4.y) << 16);
      unsigned int p1 = (unsigned int)f2h((v.z - mu) * inv * g4.z + e4.z) |
                        ((unsigned int)f2h((v.w - mu) * inv * g4.w + e4.w) << 16);
      uint2 pk; pk.x = p0; pk.y = p1;
      *reinterpret_cast<uint2*>(&zt[row * 136 + sc * 4]) = pk;
    }
  }
  __syncthreads();

  const int lr = lane & 15, lq = lane >> 4;
  const int wc = wid * 32;

  // --- gated pass-pairs: a (pass 0), b (pass 1) ---
#pragma unroll 1
  for (int pass = 0; pass < 2; pass++) {
    const ushort_t* Wg = Wcat + (size_t)(pass * 2) * 16384;
    const ushort_t* Wv = Wg + 16384;
    const float* bg = pass ? bgb : bga;
    const float* bv = pass ? bb : ba;
    ushort_t* outp = pass ? b_cm : a_cm;
    f32x4 aG[2][4], aV[2][4];
#pragma unroll
    for (int cs = 0; cs < 2; cs++)
#pragma unroll
      for (int ms = 0; ms < 4; ms++) {
        aG[cs][ms] = (f32x4){0.f, 0.f, 0.f, 0.f};
        aV[cs][ms] = (f32x4){0.f, 0.f, 0.f, 0.f};
      }
#pragma unroll
    for (int kk = 0; kk < 128; kk += 32) {
      half8 zf[4];
#pragma unroll
      for (int ms = 0; ms < 4; ms++)
        zf[ms] = ld_h8(&zt[(ms * 16 + lr) * 136 + kk + lq * 8]);
#pragma unroll
      for (int cs = 0; cs < 2; cs++) {
        half8 wg = ld_h8(Wg + (size_t)(wc + cs * 16 + lr) * CZ + kk + lq * 8);
        half8 wv = ld_h8(Wv + (size_t)(wc + cs * 16 + lr) * CZ + kk + lq * 8);
#pragma unroll
        for (int ms = 0; ms < 4; ms++) {
          aG[cs][ms] = __builtin_amdgcn_mfma_f32_16x16x32_f16(wg, zf[ms], aG[cs][ms], 0, 0, 0);
          aV[cs][ms] = __builtin_amdgcn_mfma_f32_16x16x32_f16(wv, zf[ms], aV[cs][ms], 0, 0, 0);
        }
      }
    }
    // stage epilogue into ot[c][m]
#pragma unroll
    for (int cs = 0; cs < 2; cs++)
#pragma unroll
      for (int r = 0; r < 4; r++) {
        int c = wc + cs * 16 + lq * 4 + r;
        float bgc = bg[c], bvc = bv[c];
#pragma unroll
        for (int ms = 0; ms < 4; ms++) {
          float val = (aV[cs][ms][r] + bvc) * fast_sigmoid(aG[cs][ms][r] + bgc);
          ot[c * 72 + ms * 16 + lr] = f2h(val);
        }
      }
    __syncthreads();
    // coalesced store: 128 c x 64 m, short8 per lane
#pragma unroll
    for (int p = 0; p < 4; p++) {
      int lin = p * 256 + t;
      int c = lin >> 3, mc = (lin & 7) * 8;
      *reinterpret_cast<short8*>(outp + (size_t)c * NN + m0 + mc) =
          *reinterpret_cast<const short8*>(&ot[c * 72 + mc]);
    }
    __syncthreads();  // ot reused next pass
  }

  // --- og pass ---
  {
    const ushort_t* Wg = Wcat + (size_t)4 * 16384;
    f32x4 aG[2][4];
#pragma unroll
    for (int cs = 0; cs < 2; cs++)
#pragma unroll
      for (int ms = 0; ms < 4; ms++) aG[cs][ms] = (f32x4){0.f, 0.f, 0.f, 0.f};
#pragma unroll
    for (int kk = 0; kk < 128; kk += 32) {
      half8 zf[4];
#pragma unroll
      for (int ms = 0; ms < 4; ms++)
        zf[ms] = ld_h8(&zt[(ms * 16 + lr) * 136 + kk + lq * 8]);
#pragma unroll
      for (int cs = 0; cs < 2; cs++) {
        half8 wg = ld_h8(Wg + (size_t)(wc + cs * 16 + lr) * CZ + kk + lq * 8);
#pragma unroll
        for (int ms = 0; ms < 4; ms++)
          aG[cs][ms] = __builtin_amdgcn_mfma_f32_16x16x32_f16(wg, zf[ms], aG[cs][ms], 0, 0, 0);
      }
    }
    __syncthreads();  // all waves done reading zt; reuse as [64 m][128 c]
#pragma unroll
    for (int cs = 0; cs < 2; cs++)
#pragma unroll
      for (int r = 0; r < 4; r++) {
        int c = wc + cs * 16 + lq * 4 + r;
        float bc = bog[c];
#pragma unroll
        for (int ms = 0; ms < 4; ms++)
          zt[(ms * 16 + lr) * 136 + c] = f2h(fast_sigmoid(aG[cs][ms][r] + bc));
      }
    __syncthreads();
    // coalesced store og_rm [m][c]: per instr, 4 lanes x 16B = 64B/row contiguous
    int row = t >> 2, ch = t & 3;
#pragma unroll
    for (int j = 0; j < 4; j++) {
      *reinterpret_cast<short8*>(og_rm + (size_t)(m0 + row) * CZ + j * 32 + ch * 8) =
          *reinterpret_cast<const short8*>(&zt[row * 136 + j * 32 + ch * 8]);
    }
  }
}

// ---------------- K3: per-channel einsum U_c = A_c * B_c^T ----------------
// a_cm/b_cm/u_cm are [c][i*N+k] channel-major fp16. 1-D grid, XCD swizzle.
__global__ __launch_bounds__(256) void k_tri(
    const ushort_t* __restrict__ a_cm, const ushort_t* __restrict__ b_cm,
    ushort_t* __restrict__ u_cm) {
  __shared__ ushort_t sh[18432];  // lA[128*72] + lB[128*72]; reused as out[128*136]
  ushort_t* lA = sh;
  ushort_t* lB = sh + 9216;
  const int t = threadIdx.x;
  int swz = (blockIdx.x & 7) * 256 + (blockIdx.x >> 3);
  const int ch = swz >> 4;
  const int i0 = ((swz >> 2) & 3) * 128, j0 = (swz & 3) * 128;
  const size_t base = (size_t)ch * NN;
  const int wid = t >> 6, lane = t & 63, lr = lane & 15, lq = lane >> 4;
  const int wi = (wid >> 1) * 64, wj = (wid & 1) * 64;
  f32x4 acc[4][4];
#pragma unroll
  for (int si = 0; si < 4; si++)
#pragma unroll
    for (int sj = 0; sj < 4; sj++) acc[si][sj] = (f32x4){0.f, 0.f, 0.f, 0.f};

  for (int kb = 0; kb < 8; kb++) {
    const int k0 = kb * 64;
#pragma unroll
    for (int p = 0; p < 4; p++) {
      int lin = p * 256 + t;
      int row = lin >> 3, cq = lin & 7;
      *reinterpret_cast<short8*>(&lA[row * 72 + cq * 8]) =
          *reinterpret_cast<const short8*>(a_cm + base + (size_t)(i0 + row) * NDIM + k0 + cq * 8);
      *reinterpret_cast<short8*>(&lB[row * 72 + cq * 8]) =
          *reinterpret_cast<const short8*>(b_cm + base + (size_t)(j0 + row) * NDIM + k0 + cq * 8);
    }
    __syncthreads();
#pragma unroll
    for (int ks = 0; ks < 2; ks++) {
      half8 af[4], bf[4];
#pragma unroll
      for (int s = 0; s < 4; s++) {
        af[s] = ld_h8(&lA[(wi + s * 16 + lr) * 72 + ks * 32 + lq * 8]);
        bf[s] = ld_h8(&lB[(wj + s * 16 + lr) * 72 + ks * 32 + lq * 8]);
      }
#pragma unroll
      for (int si = 0; si < 4; si++)
#pragma unroll
        for (int sj = 0; sj < 4; sj++)
          acc[si][sj] = __builtin_amdgcn_mfma_f32_16x16x32_f16(
              af[si], bf[sj], acc[si][sj], 0, 0, 0);
    }
    __syncthreads();
  }
  // epilogue -> LDS staging [128 i][128 j], stride 136
#pragma unroll
  for (int si = 0; si < 4; si++)
#pragma unroll
    for (int sj = 0; sj < 4; sj++)
#pragma unroll
      for (int r = 0; r < 4; r++) {
        int il = wi + si * 16 + lq * 4 + r;
        int jl = wj + sj * 16 + lr;
        sh[il * 136 + jl] = f2h(acc[si][sj][r]);
      }
  __syncthreads();
#pragma unroll
  for (int p = 0; p < 8; p++) {
    int lin = p * 256 + t;
    int row = lin >> 4, col = (lin & 15) * 8;
    *reinterpret_cast<short8*>(u_cm + base + (size_t)(i0 + row) * NDIM + j0 + col) =
        *reinterpret_cast<const short8*>(&sh[row * 136 + col]);
  }
}

// ---------------- K4: out = z + og * (U^T Wo^T + bo) ----------------------
__global__ __launch_bounds__(256) void k_out(
    const ushort_t* __restrict__ u_cm, const ushort_t* __restrict__ WoB,
    const ushort_t* __restrict__ og_rm, const float* __restrict__ z,
    const float* __restrict__ bo, float* __restrict__ out) {
  __shared__ ushort_t lu[128 * 136];  // [c][m-tile], stride 136
  const int t = threadIdx.x;
  const int m0 = blockIdx.x * 128;
#pragma unroll
  for (int p = 0; p < 8; p++) {
    int lin = p * 256 + t;
    int cr = lin >> 4, ch = lin & 15;
    *reinterpret_cast<short8*>(&lu[cr * 136 + ch * 8]) =
        *reinterpret_cast<const short8*>(u_cm + (size_t)cr * NN + m0 + ch * 8);
  }
  __syncthreads();
  const int wid = t >> 6, lane = t & 63, lr = lane & 15, lq = lane >> 4;
  const int wm = (wid >> 1) * 64, wc = (wid & 1) * 64;
  f32x4 acc[4][4];
#pragma unroll
  for (int ms = 0; ms < 4; ms++)
#pragma unroll
    for (int cs = 0; cs < 4; cs++) acc[ms][cs] = (f32x4){0.f, 0.f, 0.f, 0.f};
#pragma unroll
  for (int kk = 0; kk < 128; kk += 32) {
    half8 af[4];
#pragma unroll
    for (int ms = 0; ms < 4; ms++) {
      short8 v;
#pragma unroll
      for (int jj = 0; jj < 8; jj++)
        v[jj] = (short)lu[(kk + lq * 8 + jj) * 136 + wm + ms * 16 + lr];
      af[ms] = __builtin_bit_cast(half8, v);
    }
#pragma unroll
    for (int cs = 0; cs < 4; cs++) {
      half8 bf = ld_h8(WoB + (size_t)(wc + cs * 16 + lr) * CZ + kk + lq * 8);
#pragma unroll
      for (int ms = 0; ms < 4; ms++)
        acc[ms][cs] = __builtin_amdgcn_mfma_f32_16x16x32_f16(
            af[ms], bf, acc[ms][cs], 0, 0, 0);
    }
  }
#pragma unroll
  for (int ms = 0; ms < 4; ms++)
#pragma unroll
    for (int cs = 0; cs < 4; cs++)
#pragma unroll
      for (int r = 0; r < 4; r++) {
        int m = m0 + wm + ms * 16 + lq * 4 + r;
        int cp = wc + cs * 16 + lr;
        float val = acc[ms][cs][r] + bo[cp];
        float gate = h2f(og_rm[(size_t)m * CZ + cp]);
        out[(size_t)m * CZ + cp] = z[(size_t)m * CZ + cp] + gate * val;
      }
}

extern "C" void kernel_launch(void* const* d_in, const int* in_sizes, int n_in,
                              void* d_out, int out_size, void* d_ws, size_t ws_size,
                              hipStream_t stream) {
  const float* z = (const float*)d_in[0];
  const float* gamma = (const float*)d_in[1];
  const float* beta = (const float*)d_in[2];
  const float* Wa = (const float*)d_in[3];  const float* ba = (const float*)d_in[4];
  const float* Wb = (const float*)d_in[5];  const float* bb = (const float*)d_in[6];
  const float* Wga = (const float*)d_in[7]; const float* bga = (const float*)d_in[8];
  const float* Wgb = (const float*)d_in[9]; const float* bgb = (const float*)d_in[10];
  const float* Wo = (const float*)d_in[11]; const float* bo = (const float*)d_in[12];
  const float* Wog = (const float*)d_in[13];const float* bog = (const float*)d_in[14];

  char* ws = (char*)d_ws;
  ushort_t* a_cm = (ushort_t*)(ws);                     // 64 MiB [c][m]
  ushort_t* b_cm = (ushort_t*)(ws + 67108864);          // 64 MiB [c][m]
  ushort_t* og_rm = (ushort_t*)(ws + 134217728);        // 64 MiB [m][c]
  ushort_t* u_cm = (ushort_t*)(ws + 201326592);         // 64 MiB [c][i*N+j]
  ushort_t* Wcat = (ushort_t*)(ws + 268435456);         // 192 KiB

  k_wconv<<<384, 256, 0, stream>>>(Wga, Wa, Wgb, Wb, Wog, Wo, Wcat);
  k_front<<<NN / 64, 256, 0, stream>>>(z, gamma, beta, Wcat, bga, ba, bgb, bb, bog,
                                       a_cm, b_cm, og_rm);
  k_tri<<<2048, 256, 0, stream>>>(a_cm, b_cm, u_cm);
  k_out<<<NN / 128, 256, 0, stream>>>(u_cm, Wcat + 5 * 16384, og_rm, z, bo, (float*)d_out);
}

// Round 5
// 376.140 us; speedup vs baseline: 1.4520x; 1.0219x over previous
//
#include <hip/hip_runtime.h>

#define NDIM 512
#define CZ 128
#define NN (NDIM*NDIM)

typedef __attribute__((ext_vector_type(8))) _Float16 half8;
typedef __attribute__((ext_vector_type(8))) short short8;
typedef __attribute__((ext_vector_type(4))) float f32x4;
typedef unsigned short ushort_t;

__device__ __forceinline__ ushort_t f2h(float f) {
  _Float16 h = (_Float16)f;
  return __builtin_bit_cast(unsigned short, h);
}
__device__ __forceinline__ float h2f(ushort_t u) {
  return (float)__builtin_bit_cast(_Float16, u);
}
__device__ __forceinline__ float fast_sigmoid(float x) {
  return __builtin_amdgcn_rcpf(1.0f + __expf(-x));
}
__device__ __forceinline__ half8 ld_h8(const ushort_t* p) {
  return *reinterpret_cast<const half8*>(p);
}

// ---------------- K0: convert weights to fp16, concatenated ----------------
// Wcat order: 0:Wga 1:Wa 2:Wgb 3:Wb 4:Wog 5:Wo
__global__ __launch_bounds__(256) void k_wconv(
    const float* __restrict__ Wga, const float* __restrict__ Wa,
    const float* __restrict__ Wgb, const float* __restrict__ Wb,
    const float* __restrict__ Wog, const float* __restrict__ Wo,
    ushort_t* __restrict__ Wcat) {
  int idx = blockIdx.x * 256 + threadIdx.x;  // 6*16384 total
  const float* srcs[6] = {Wga, Wa, Wgb, Wb, Wog, Wo};
  float v = srcs[idx >> 14][idx & 16383];
  Wcat[idx] = f2h(v);
}

// ---------------- K_front: fused LN + 5 projections ------------------------
__global__ __launch_bounds__(256, 4) void k_front(
    const float* __restrict__ z, const float* __restrict__ gamma,
    const float* __restrict__ beta, const ushort_t* __restrict__ Wcat,
    const float* __restrict__ bga, const float* __restrict__ ba,
    const float* __restrict__ bgb, const float* __restrict__ bb,
    const float* __restrict__ bog,
    ushort_t* __restrict__ a_cm, ushort_t* __restrict__ b_cm,
    ushort_t* __restrict__ og_rm) {
  __shared__ ushort_t zt[64 * 136];  // [64 m][128 k] fp16, stride 136
  __shared__ ushort_t ot[128 * 72];  // staging [128 c][64 m], stride 72
  const int t = threadIdx.x;
  const int m0 = blockIdx.x * 64;
  const int lane = t & 63, wid = t >> 6;

  // --- LN phase ---
  {
    const int sub = lane >> 5;
    const int sc = lane & 31;
    float4 g4 = *reinterpret_cast<const float4*>(gamma + sc * 4);
    float4 e4 = *reinterpret_cast<const float4*>(beta + sc * 4);
#pragma unroll
    for (int it = 0; it < 8; it++) {
      int row = wid * 16 + it * 2 + sub;
      float4 v = *reinterpret_cast<const float4*>(z + (size_t)(m0 + row) * CZ + sc * 4);
      float s = v.x + v.y + v.z + v.w;
      float ss = v.x * v.x + v.y * v.y + v.z * v.z + v.w * v.w;
#pragma unroll
      for (int o = 1; o < 32; o <<= 1) { s += __shfl_xor(s, o); ss += __shfl_xor(ss, o); }
      float mu = s * (1.0f / CZ);
      float inv = rsqrtf(fmaxf(ss * (1.0f / CZ) - mu * mu, 0.0f) + 1e-5f);
      unsigned int p0 = (unsigned int)f2h((v.x - mu) * inv * g4.x + e4.x) |
                        ((unsigned int)f2h((v.y - mu) * inv * g4.y + e4.y) << 16);
      unsigned int p1 = (unsigned int)f2h((v.z - mu) * inv * g4.z + e4.z) |
                        ((unsigned int)f2h((v.w - mu) * inv * g4.w + e4.w) << 16);
      uint2 pk; pk.x = p0; pk.y = p1;
      *reinterpret_cast<uint2*>(&zt[row * 136 + sc * 4]) = pk;
    }
  }
  __syncthreads();

  const int lr = lane & 15, lq = lane >> 4;
  const int wc = wid * 32;

  // --- gated pass-pairs: a (pass 0), b (pass 1) ---
#pragma unroll 1
  for (int pass = 0; pass < 2; pass++) {
    const ushort_t* Wg = Wcat + (size_t)(pass * 2) * 16384;
    const ushort_t* Wv = Wg + 16384;
    const float* bg = pass ? bgb : bga;
    const float* bv = pass ? bb : ba;
    ushort_t* outp = pass ? b_cm : a_cm;
    f32x4 aG[2][4], aV[2][4];
#pragma unroll
    for (int cs = 0; cs < 2; cs++)
#pragma unroll
      for (int ms = 0; ms < 4; ms++) {
        aG[cs][ms] = (f32x4){0.f, 0.f, 0.f, 0.f};
        aV[cs][ms] = (f32x4){0.f, 0.f, 0.f, 0.f};
      }
#pragma unroll
    for (int kk = 0; kk < 128; kk += 32) {
      half8 zf[4];
#pragma unroll
      for (int ms = 0; ms < 4; ms++)
        zf[ms] = ld_h8(&zt[(ms * 16 + lr) * 136 + kk + lq * 8]);
#pragma unroll
      for (int cs = 0; cs < 2; cs++) {
        half8 wg = ld_h8(Wg + (size_t)(wc + cs * 16 + lr) * CZ + kk + lq * 8);
        half8 wv = ld_h8(Wv + (size_t)(wc + cs * 16 + lr) * CZ + kk + lq * 8);
#pragma unroll
        for (int ms = 0; ms < 4; ms++) {
          aG[cs][ms] = __builtin_amdgcn_mfma_f32_16x16x32_f16(wg, zf[ms], aG[cs][ms], 0, 0, 0);
          aV[cs][ms] = __builtin_amdgcn_mfma_f32_16x16x32_f16(wv, zf[ms], aV[cs][ms], 0, 0, 0);
        }
      }
    }
#pragma unroll
    for (int cs = 0; cs < 2; cs++)
#pragma unroll
      for (int r = 0; r < 4; r++) {
        int c = wc + cs * 16 + lq * 4 + r;
        float bgc = bg[c], bvc = bv[c];
#pragma unroll
        for (int ms = 0; ms < 4; ms++) {
          float val = (aV[cs][ms][r] + bvc) * fast_sigmoid(aG[cs][ms][r] + bgc);
          ot[c * 72 + ms * 16 + lr] = f2h(val);
        }
      }
    __syncthreads();
#pragma unroll
    for (int p = 0; p < 4; p++) {
      int lin = p * 256 + t;
      int c = lin >> 3, mc = (lin & 7) * 8;
      *reinterpret_cast<short8*>(outp + (size_t)c * NN + m0 + mc) =
          *reinterpret_cast<const short8*>(&ot[c * 72 + mc]);
    }
    __syncthreads();  // ot reused next pass
  }

  // --- og pass ---
  {
    const ushort_t* Wg = Wcat + (size_t)4 * 16384;
    f32x4 aG[2][4];
#pragma unroll
    for (int cs = 0; cs < 2; cs++)
#pragma unroll
      for (int ms = 0; ms < 4; ms++) aG[cs][ms] = (f32x4){0.f, 0.f, 0.f, 0.f};
#pragma unroll
    for (int kk = 0; kk < 128; kk += 32) {
      half8 zf[4];
#pragma unroll
      for (int ms = 0; ms < 4; ms++)
        zf[ms] = ld_h8(&zt[(ms * 16 + lr) * 136 + kk + lq * 8]);
#pragma unroll
      for (int cs = 0; cs < 2; cs++) {
        half8 wg = ld_h8(Wg + (size_t)(wc + cs * 16 + lr) * CZ + kk + lq * 8);
#pragma unroll
        for (int ms = 0; ms < 4; ms++)
          aG[cs][ms] = __builtin_amdgcn_mfma_f32_16x16x32_f16(wg, zf[ms], aG[cs][ms], 0, 0, 0);
      }
    }
    __syncthreads();  // all waves done reading zt; reuse as [64 m][128 c]
#pragma unroll
    for (int cs = 0; cs < 2; cs++)
#pragma unroll
      for (int r = 0; r < 4; r++) {
        int c = wc + cs * 16 + lq * 4 + r;
        float bc = bog[c];
#pragma unroll
        for (int ms = 0; ms < 4; ms++)
          zt[(ms * 16 + lr) * 136 + c] = f2h(fast_sigmoid(aG[cs][ms][r] + bc));
      }
    __syncthreads();
    int row = t >> 2, ch = t & 3;
#pragma unroll
    for (int j = 0; j < 4; j++) {
      *reinterpret_cast<short8*>(og_rm + (size_t)(m0 + row) * CZ + j * 32 + ch * 8) =
          *reinterpret_cast<const short8*>(&zt[row * 136 + j * 32 + ch * 8]);
    }
  }
}

// ---------------- K3: per-channel einsum U_c = A_c * B_c^T ----------------
__global__ __launch_bounds__(256) void k_tri(
    const ushort_t* __restrict__ a_cm, const ushort_t* __restrict__ b_cm,
    ushort_t* __restrict__ u_cm) {
  __shared__ ushort_t sh[18432];  // lA[128*72] + lB[128*72]; reused as out[128*136]
  ushort_t* lA = sh;
  ushort_t* lB = sh + 9216;
  const int t = threadIdx.x;
  int swz = (blockIdx.x & 7) * 256 + (blockIdx.x >> 3);
  const int ch = swz >> 4;
  const int i0 = ((swz >> 2) & 3) * 128, j0 = (swz & 3) * 128;
  const size_t base = (size_t)ch * NN;
  const int wid = t >> 6, lane = t & 63, lr = lane & 15, lq = lane >> 4;
  const int wi = (wid >> 1) * 64, wj = (wid & 1) * 64;
  f32x4 acc[4][4];
#pragma unroll
  for (int si = 0; si < 4; si++)
#pragma unroll
    for (int sj = 0; sj < 4; sj++) acc[si][sj] = (f32x4){0.f, 0.f, 0.f, 0.f};

  for (int kb = 0; kb < 8; kb++) {
    const int k0 = kb * 64;
#pragma unroll
    for (int p = 0; p < 4; p++) {
      int lin = p * 256 + t;
      int row = lin >> 3, cq = lin & 7;
      *reinterpret_cast<short8*>(&lA[row * 72 + cq * 8]) =
          *reinterpret_cast<const short8*>(a_cm + base + (size_t)(i0 + row) * NDIM + k0 + cq * 8);
      *reinterpret_cast<short8*>(&lB[row * 72 + cq * 8]) =
          *reinterpret_cast<const short8*>(b_cm + base + (size_t)(j0 + row) * NDIM + k0 + cq * 8);
    }
    __syncthreads();
#pragma unroll
    for (int ks = 0; ks < 2; ks++) {
      half8 af[4], bf[4];
#pragma unroll
      for (int s = 0; s < 4; s++) {
        af[s] = ld_h8(&lA[(wi + s * 16 + lr) * 72 + ks * 32 + lq * 8]);
        bf[s] = ld_h8(&lB[(wj + s * 16 + lr) * 72 + ks * 32 + lq * 8]);
      }
#pragma unroll
      for (int si = 0; si < 4; si++)
#pragma unroll
        for (int sj = 0; sj < 4; sj++)
          acc[si][sj] = __builtin_amdgcn_mfma_f32_16x16x32_f16(
              af[si], bf[sj], acc[si][sj], 0, 0, 0);
    }
    __syncthreads();
  }
#pragma unroll
  for (int si = 0; si < 4; si++)
#pragma unroll
    for (int sj = 0; sj < 4; sj++)
#pragma unroll
      for (int r = 0; r < 4; r++) {
        int il = wi + si * 16 + lq * 4 + r;
        int jl = wj + sj * 16 + lr;
        sh[il * 136 + jl] = f2h(acc[si][sj][r]);
      }
  __syncthreads();
#pragma unroll
  for (int p = 0; p < 8; p++) {
    int lin = p * 256 + t;
    int row = lin >> 4, col = (lin & 15) * 8;
    *reinterpret_cast<short8*>(u_cm + base + (size_t)(i0 + row) * NDIM + j0 + col) =
        *reinterpret_cast<const short8*>(&sh[row * 136 + col]);
  }
}

// ---------------- K4: out = z + og * (U^T Wo^T + bo) ----------------------
// 64 m x 128 cp per block; u staged TRANSPOSED in LDS (ut[m][c]) so A-frags
// are single ds_read_b128. Transpose paid at LDS-write time conflict-free:
// consecutive lanes take consecutive c (scattered global 16B reads, L2-local
// within block), each ds_write_b16 instr writes 128 contiguous bytes.
__global__ __launch_bounds__(256, 6) void k_out(
    const ushort_t* __restrict__ u_cm, const ushort_t* __restrict__ WoB,
    const ushort_t* __restrict__ og_rm, const float* __restrict__ z,
    const float* __restrict__ bo, float* __restrict__ out) {
  __shared__ ushort_t ut[64 * 136];  // [m-local][c], stride 136
  const int t = threadIdx.x;
  const int m0 = blockIdx.x * 64;
  // stage transposed
  {
    const int c = t & 127;
    const int cb = t >> 7;  // 0 or 1
#pragma unroll
    for (int p = 0; p < 4; p++) {
      int chunk = cb * 4 + p;  // m-chunk of 8
      short8 v = *reinterpret_cast<const short8*>(u_cm + (size_t)c * NN + m0 + chunk * 8);
#pragma unroll
      for (int jj = 0; jj < 8; jj++)
        ut[(chunk * 8 + jj) * 136 + c] = (ushort_t)v[jj];
    }
  }
  __syncthreads();
  const int wid = t >> 6, lane = t & 63, lr = lane & 15, lq = lane >> 4;
  const int wm = wid * 16;  // wave's 16 m-rows
  f32x4 acc[8];
#pragma unroll
  for (int cs = 0; cs < 8; cs++) acc[cs] = (f32x4){0.f, 0.f, 0.f, 0.f};
#pragma unroll
  for (int kk = 0; kk < 128; kk += 32) {
    half8 af = ld_h8(&ut[(wm + lr) * 136 + kk + lq * 8]);
#pragma unroll
    for (int cs = 0; cs < 8; cs++) {
      half8 bf = ld_h8(WoB + (size_t)(cs * 16 + lr) * CZ + kk + lq * 8);
      acc[cs] = __builtin_amdgcn_mfma_f32_16x16x32_f16(af, bf, acc[cs], 0, 0, 0);
    }
  }
#pragma unroll
  for (int cs = 0; cs < 8; cs++) {
    int cp = cs * 16 + lr;
    float bc = bo[cp];
#pragma unroll
    for (int r = 0; r < 4; r++) {
      int m = m0 + wm + lq * 4 + r;
      float val = acc[cs][r] + bc;
      float gate = h2f(og_rm[(size_t)m * CZ + cp]);
      out[(size_t)m * CZ + cp] = z[(size_t)m * CZ + cp] + gate * val;
    }
  }
}

extern "C" void kernel_launch(void* const* d_in, const int* in_sizes, int n_in,
                              void* d_out, int out_size, void* d_ws, size_t ws_size,
                              hipStream_t stream) {
  const float* z = (const float*)d_in[0];
  const float* gamma = (const float*)d_in[1];
  const float* beta = (const float*)d_in[2];
  const float* Wa = (const float*)d_in[3];  const float* ba = (const float*)d_in[4];
  const float* Wb = (const float*)d_in[5];  const float* bb = (const float*)d_in[6];
  const float* Wga = (const float*)d_in[7]; const float* bga = (const float*)d_in[8];
  const float* Wgb = (const float*)d_in[9]; const float* bgb = (const float*)d_in[10];
  const float* Wo = (const float*)d_in[11]; const float* bo = (const float*)d_in[12];
  const float* Wog = (const float*)d_in[13];const float* bog = (const float*)d_in[14];

  char* ws = (char*)d_ws;
  ushort_t* a_cm = (ushort_t*)(ws);                     // 64 MiB [c][m]
  ushort_t* b_cm = (ushort_t*)(ws + 67108864);          // 64 MiB [c][m]
  ushort_t* og_rm = (ushort_t*)(ws + 134217728);        // 64 MiB [m][c]
  ushort_t* u_cm = (ushort_t*)(ws + 201326592);         // 64 MiB [c][i*N+j]
  ushort_t* Wcat = (ushort_t*)(ws + 268435456);         // 192 KiB

  k_wconv<<<384, 256, 0, stream>>>(Wga, Wa, Wgb, Wb, Wog, Wo, Wcat);
  k_front<<<NN / 64, 256, 0, stream>>>(z, gamma, beta, Wcat, bga, ba, bgb, bb, bog,
                                       a_cm, b_cm, og_rm);
  k_tri<<<2048, 256, 0, stream>>>(a_cm, b_cm, u_cm);
  k_out<<<NN / 64, 256, 0, stream>>>(u_cm, Wcat + 5 * 16384, og_rm, z, bo, (float*)d_out);
}